// Round 12
// baseline (1231.181 us; speedup 1.0000x reference)
//
#include <hip/hip_runtime.h>

#define TT 512
#define BB 64
#define EE 300
#define HH 150
#define G3 450
#define AT 75
#define NW 28          // v2f pairs per row-slice (56-float h window)

typedef float v2f __attribute__((ext_vector_type(2)));

__device__ __forceinline__ float fast_rcp(float x) { return __builtin_amdgcn_rcpf(x); }
__device__ __forceinline__ float sigmoid_f(float x) { return fast_rcp(1.f + __expf(-x)); }
__device__ __forceinline__ float tanh_f(float x) {
  float e = __expf(2.f * x);
  return 1.f - 2.f * fast_rcp(e + 1.f);
}

// ---------------- weight prep ----------------
// Wih0T [300][450], Whh0T/Whh1T [150][450] (k-major), Wih1Tp [152][450] padded.
__global__ void k_prep(const float* __restrict__ Wih0, const float* __restrict__ Whh0,
                       const float* __restrict__ Wih1, const float* __restrict__ Whh1,
                       const float* __restrict__ W1,   const float* __restrict__ fc1w,
                       float* __restrict__ Wih0T, float* __restrict__ Whh0T,
                       float* __restrict__ Wih1Tp, float* __restrict__ Whh1T,
                       float* __restrict__ W1T,   float* __restrict__ fc1T) {
  int tid = blockIdx.x * blockDim.x + threadIdx.x;
  int nt = gridDim.x * blockDim.x;
  for (int i = tid; i < G3 * EE; i += nt) { int r = i / EE, c = i - r * EE; Wih0T[c * G3 + r] = Wih0[i]; }
  for (int i = tid; i < G3 * HH; i += nt) { int r = i / HH, c = i - r * HH; Whh0T[c * G3 + r] = Whh0[i]; }
  for (int i = tid; i < 152 * G3; i += nt) {
    int k = i / G3, g = i - k * G3;
    Wih1Tp[i] = (k < HH) ? Wih1[g * HH + k] : 0.f;
  }
  for (int i = tid; i < G3 * HH; i += nt) { int r = i / HH, c = i - r * HH; Whh1T[c * G3 + r] = Whh1[i]; }
  for (int i = tid; i < AT * HH; i += nt) { int r = i / HH, c = i - r * HH; W1T[c * AT + r] = W1[i]; }
  for (int i = tid; i < HH * HH; i += nt) { int r = i / HH, c = i - r * HH; fc1T[c * HH + r] = fc1w[i]; }
}

// ---------------- layer-0 input projection: gather + [32768,300]@[300,450] ----------------
// Early-exit: each 32-row tile is one (b, t-range); if t0 >= len[b] the rows
// are never read by k_rec (it only reads t < len) -> skip (~48% of tiles).
__global__ __launch_bounds__(128, 2) void k_xw0(const int* __restrict__ texts,
                                                const int* __restrict__ lengths,
                                                const float* __restrict__ emb,
                                                const float* __restrict__ WihT,
                                                const float* __restrict__ bih,
                                                float* __restrict__ xw) {
  const int row0 = blockIdx.x * 32;
  if ((row0 & 511) >= lengths[row0 >> 9]) return;
  __shared__ __align__(16) float a_lds[32 * EE];
  const int tid = threadIdx.x;
  for (int p = tid; p < 32 * EE; p += 128) {
    int r = p / EE, e = p - r * EE;
    a_lds[p] = emb[(size_t)texts[row0 + r] * EE + e];
  }
  __syncthreads();
  const int g0 = tid, g1 = tid + 128, g2 = tid + 256;
  const bool has3 = (tid + 384) < G3;
  const int g3 = has3 ? tid + 384 : 0;
  float acc0[32], acc1[32], acc2[32], acc3[32];
#pragma unroll
  for (int r = 0; r < 32; ++r) { acc0[r] = 0.f; acc1[r] = 0.f; acc2[r] = 0.f; acc3[r] = 0.f; }
  const float4* a4 = reinterpret_cast<const float4*>(a_lds);
  for (int k = 0; k < EE; k += 4) {
    float wA[4], wB[4], wC[4], wD[4];
#pragma unroll
    for (int i = 0; i < 4; ++i) {
      const float* wr = WihT + (size_t)(k + i) * G3;
      wA[i] = wr[g0]; wB[i] = wr[g1]; wC[i] = wr[g2]; wD[i] = wr[g3];
    }
#pragma unroll
    for (int r = 0; r < 32; ++r) {
      const float4 av = a4[r * 75 + (k >> 2)];
      acc0[r] = fmaf(av.x, wA[0], acc0[r]); acc0[r] = fmaf(av.y, wA[1], acc0[r]);
      acc0[r] = fmaf(av.z, wA[2], acc0[r]); acc0[r] = fmaf(av.w, wA[3], acc0[r]);
      acc1[r] = fmaf(av.x, wB[0], acc1[r]); acc1[r] = fmaf(av.y, wB[1], acc1[r]);
      acc1[r] = fmaf(av.z, wB[2], acc1[r]); acc1[r] = fmaf(av.w, wB[3], acc1[r]);
      acc2[r] = fmaf(av.x, wC[0], acc2[r]); acc2[r] = fmaf(av.y, wC[1], acc2[r]);
      acc2[r] = fmaf(av.z, wC[2], acc2[r]); acc2[r] = fmaf(av.w, wC[3], acc2[r]);
      acc3[r] = fmaf(av.x, wD[0], acc3[r]); acc3[r] = fmaf(av.y, wD[1], acc3[r]);
      acc3[r] = fmaf(av.z, wD[2], acc3[r]); acc3[r] = fmaf(av.w, wD[3], acc3[r]);
    }
  }
  const float b0 = bih[g0], b1 = bih[g1], b2 = bih[g2], b3 = bih[g3];
#pragma unroll
  for (int r = 0; r < 32; ++r) {
    float* o = xw + (size_t)(row0 + r) * G3;
    o[g0] = acc0[r] + b0; o[g1] = acc1[r] + b1; o[g2] = acc2[r] + b2;
    if (has3) o[g3] = acc3[r] + b3;
  }
}

// ---------------- layer-1 input projection: [32768,150]@[150,450] ----------------
__global__ __launch_bounds__(128, 2) void k_xw1(const float* __restrict__ in,
                                                const int* __restrict__ lengths,
                                                const float* __restrict__ WihTp,
                                                const float* __restrict__ bih,
                                                float* __restrict__ xw) {
  const int row0 = blockIdx.x * 32;
  if ((row0 & 511) >= lengths[row0 >> 9]) return;
  __shared__ __align__(16) float a_lds[32 * 152];
  const int tid = threadIdx.x;
  for (int p = tid; p < 32 * 152; p += 128) {
    int r = p / 152, e = p - r * 152;
    a_lds[p] = (e < HH) ? in[(size_t)(row0 + r) * HH + e] : 0.f;
  }
  __syncthreads();
  const int g0 = tid, g1 = tid + 128, g2 = tid + 256;
  const bool has3 = (tid + 384) < G3;
  const int g3 = has3 ? tid + 384 : 0;
  float acc0[32], acc1[32], acc2[32], acc3[32];
#pragma unroll
  for (int r = 0; r < 32; ++r) { acc0[r] = 0.f; acc1[r] = 0.f; acc2[r] = 0.f; acc3[r] = 0.f; }
  const float4* a4 = reinterpret_cast<const float4*>(a_lds);
  for (int k = 0; k < 152; k += 4) {
    float wA[4], wB[4], wC[4], wD[4];
#pragma unroll
    for (int i = 0; i < 4; ++i) {
      const float* wr = WihTp + (size_t)(k + i) * G3;
      wA[i] = wr[g0]; wB[i] = wr[g1]; wC[i] = wr[g2]; wD[i] = wr[g3];
    }
#pragma unroll
    for (int r = 0; r < 32; ++r) {
      const float4 av = a4[r * 38 + (k >> 2)];
      acc0[r] = fmaf(av.x, wA[0], acc0[r]); acc0[r] = fmaf(av.y, wA[1], acc0[r]);
      acc0[r] = fmaf(av.z, wA[2], acc0[r]); acc0[r] = fmaf(av.w, wA[3], acc0[r]);
      acc1[r] = fmaf(av.x, wB[0], acc1[r]); acc1[r] = fmaf(av.y, wB[1], acc1[r]);
      acc1[r] = fmaf(av.z, wB[2], acc1[r]); acc1[r] = fmaf(av.w, wB[3], acc1[r]);
      acc2[r] = fmaf(av.x, wC[0], acc2[r]); acc2[r] = fmaf(av.y, wC[1], acc2[r]);
      acc2[r] = fmaf(av.z, wC[2], acc2[r]); acc2[r] = fmaf(av.w, wC[3], acc2[r]);
      acc3[r] = fmaf(av.x, wD[0], acc3[r]); acc3[r] = fmaf(av.y, wD[1], acc3[r]);
      acc3[r] = fmaf(av.z, wD[2], acc3[r]); acc3[r] = fmaf(av.w, wD[3], acc3[r]);
    }
  }
  const float b0 = bih[g0], b1 = bih[g1], b2 = bih[g2], b3 = bih[g3];
#pragma unroll
  for (int r = 0; r < 32; ++r) {
    float* o = xw + (size_t)(row0 + r) * G3;
    o[g0] = acc0[r] + b0; o[g1] = acc1[r] + b1; o[g2] = acc2[r] + b2;
    if (has3) o[g3] = acc3[r] + b3;
  }
}

// ---------------- GRU recurrence (round-5 form + xw register double-buffer) ----------------
// Thread (g, j) owns gate rows {j, j+150, j+300} restricted to k-slice g.
// Round-11 ruled out VALU issue (pkfma null) and rounds 4/5 ruled out LDS
// throughput; the remaining step-time gap is exposed xw[t] load latency
// (xwbuf = 59MB, L2-miss/L3-hit ~500-900cy; old cover was only the ~350cy
// matvec). Fix: issue xw[t+1] loads at iteration t -- the vmcnt wait moves a
// full iteration downstream, fully covering L3 latency.
__global__ __launch_bounds__(512, 2) void k_rec(const float* __restrict__ WhhT,
                                                const float* __restrict__ bhh,
                                                const float* __restrict__ xw,
                                                const int* __restrict__ lengths,
                                                float* __restrict__ out) {
  const int b = blockIdx.x;
  const int tid = threadIdx.x;
  __shared__ __align__(16) float h_lds[152];      // 150 used; pad zeros
  __shared__ float part[2][G3 + 6];
  const int len = lengths[b];

  int g = tid / 150;                               // 0,1,2 worker slices; 3 = inactive
  const bool worker = g < 3;
  const int gg = worker ? g : 2;
  const int j = worker ? (tid - 150 * g) : 0;
  const int kreal_end = (gg == 2) ? 150 : 48 * (gg + 1);
  const int h4base = 12 * gg;                      // float4 index of window start (48g/4)

  v2f w[3][NW];
#pragma unroll
  for (int r = 0; r < 3; ++r) {
    const int row = j + 150 * r;
#pragma unroll
    for (int q = 0; q < NW; ++q) {
      const int k0 = 48 * gg + 2 * q;
      const int k1 = k0 + 1;
      w[r][q][0] = (worker && k0 < kreal_end) ? WhhT[k0 * G3 + row] : 0.f;
      w[r][q][1] = (worker && k1 < kreal_end) ? WhhT[k1 * G3 + row] : 0.f;
    }
  }
  const float bias_r = bhh[j];
  const float bias_z = bhh[j + 150];
  const float bias_n = bhh[j + 300];

  for (int p = tid; p < 152; p += 512) h_lds[p] = 0.f;
  float h_reg = 0.f;                               // h[j] for g0 threads
  __syncthreads();

  const float* xwb = xw + (size_t)b * TT * G3;
  float* outb = out + (size_t)b * TT * HH;
  const float4* h4 = reinterpret_cast<const float4*>(h_lds);

  // preload xw[0]
  float xr = 0.f, xz = 0.f, xn = 0.f;
  if (tid < HH) {
    xr = xwb[tid]; xz = xwb[tid + HH]; xn = xwb[tid + 2 * HH];
  }

  for (int t = 0; t < len; ++t) {
    // issue next-step xw loads NOW (branchless clamped index); the wait lands
    // a full iteration later -> L3 latency fully hidden
    float nxr = 0.f, nxz = 0.f, nxn = 0.f;
    if (tid < HH) {
      const int tn = (t + 1 < len) ? (t + 1) : (len - 1);
      const float* xwt = xwb + (size_t)tn * G3;
      nxr = xwt[tid]; nxz = xwt[tid + HH]; nxn = xwt[tid + 2 * HH];
    }
    v2f ar0 = {0.f, 0.f}, ar1 = {0.f, 0.f};
    v2f az0 = {0.f, 0.f}, az1 = {0.f, 0.f};
    v2f an0 = {0.f, 0.f}, an1 = {0.f, 0.f};
#pragma unroll
    for (int q = 0; q < 14; ++q) {
      const float4 hv = h4[h4base + q];
      const v2f hx = {hv.x, hv.y};
      const v2f hy = {hv.z, hv.w};
      ar0 = __builtin_elementwise_fma(w[0][2 * q],     hx, ar0);
      ar1 = __builtin_elementwise_fma(w[0][2 * q + 1], hy, ar1);
      az0 = __builtin_elementwise_fma(w[1][2 * q],     hx, az0);
      az1 = __builtin_elementwise_fma(w[1][2 * q + 1], hy, az1);
      an0 = __builtin_elementwise_fma(w[2][2 * q],     hx, an0);
      an1 = __builtin_elementwise_fma(w[2][2 * q + 1], hy, an1);
    }
    const float pr = (ar0[0] + ar0[1]) + (ar1[0] + ar1[1]);
    const float pz = (az0[0] + az0[1]) + (az1[0] + az1[1]);
    const float pn = (an0[0] + an0[1]) + (an1[0] + an1[1]);
    if (worker && g > 0) {
      part[g - 1][j] = pr;
      part[g - 1][j + 150] = pz;
      part[g - 1][j + 300] = pn;
    }
    __syncthreads();

    if (tid < HH) {
      const float hr = pr + part[0][tid] + part[1][tid] + bias_r;
      const float hz = pz + part[0][tid + 150] + part[1][tid + 150] + bias_z;
      const float hn = pn + part[0][tid + 300] + part[1][tid + 300] + bias_n;
      const float r = sigmoid_f(xr + hr);
      const float z = sigmoid_f(xz + hz);
      const float n = tanh_f(xn + r * hn);
      const float hnew = (1.f - z) * n + z * h_reg;
      h_reg = hnew;
      h_lds[tid] = hnew;
      outb[(size_t)t * HH + tid] = hnew;
    }
    __syncthreads();
    xr = nxr; xz = nxz; xn = nxn;
  }
  // pad_packed_sequence pads with zeros past length
  const int rem = (TT - len) * HH;
  float* outp = outb + (size_t)len * HH;
  for (int p = tid; p < rem; p += 512) outp[p] = 0.f;
}

// ---------------- attention scores: tanh(out1 @ W1^T) @ w2^T ----------------
// Early-exit: rows past len have out1 == 0 -> tanh(0)@w2 == 0.
__global__ __launch_bounds__(256) void k_scores(const float* __restrict__ out1,
                                                const int* __restrict__ lengths,
                                                const float* __restrict__ W1T,
                                                const float* __restrict__ w2,
                                                float* __restrict__ scores) {
  const int row0 = blockIdx.x * 32;
  const int tid = threadIdx.x;
  if ((row0 & 511) >= lengths[row0 >> 9]) {
    if (tid < 32) scores[row0 + tid] = 0.f;
    return;
  }
  __shared__ float sc[32];
  if (tid < 32) sc[tid] = 0.f;
  __syncthreads();
  for (int p = tid; p < 32 * AT; p += 256) {
    const int r = p / AT, a = p - r * AT;
    const float* x = out1 + (size_t)(row0 + r) * HH;
    float a0 = 0.f, a1 = 0.f;
    for (int k = 0; k < HH; k += 2) {
      a0 = fmaf(W1T[k * AT + a], x[k], a0);
      a1 = fmaf(W1T[(k + 1) * AT + a], x[k + 1], a1);
    }
    atomicAdd(&sc[r], tanh_f(a0 + a1) * w2[a]);
  }
  __syncthreads();
  if (tid < 32) scores[row0 + tid] = sc[tid];
}

// ---------------- softmax + context + classifier head (per batch) ----------------
__global__ __launch_bounds__(512) void k_final(const float* __restrict__ out1,
                                               const float* __restrict__ scores,
                                               const float* __restrict__ fc1T,
                                               const float* __restrict__ fc1b,
                                               const float* __restrict__ fc2w,
                                               const float* __restrict__ fc2b,
                                               float* __restrict__ logits) {
  const int b = blockIdx.x;
  const int tid = threadIdx.x;
  __shared__ float attn[TT];
  __shared__ float red[16];
  __shared__ float ctx[152];
  __shared__ float h1[152];

  float sv = scores[b * TT + tid];
  float m = sv;
#pragma unroll
  for (int off = 32; off > 0; off >>= 1) m = fmaxf(m, __shfl_xor(m, off));
  const int wave = tid >> 6;
  if ((tid & 63) == 0) red[wave] = m;
  __syncthreads();
  if (tid == 0) {
    float mm = red[0];
#pragma unroll
    for (int i = 1; i < 8; ++i) mm = fmaxf(mm, red[i]);
    red[8] = mm;
  }
  __syncthreads();
  const float e = __expf(sv - red[8]);
  attn[tid] = e;
  float zz = e;
#pragma unroll
  for (int off = 32; off > 0; off >>= 1) zz += __shfl_xor(zz, off);
  if ((tid & 63) == 0) red[wave] = zz;
  __syncthreads();
  if (tid == 0) {
    float ss = 0.f;
#pragma unroll
    for (int i = 0; i < 8; ++i) ss += red[i];
    red[9] = ss;
  }
  __syncthreads();
  const float invZ = 1.f / red[9];

  if (tid < HH) {
    const float* o1b = out1 + (size_t)b * TT * HH;
    float c0 = 0.f, c1 = 0.f, c2 = 0.f, c3 = 0.f;
    for (int t = 0; t < TT; t += 4) {
      c0 = fmaf(attn[t + 0], o1b[(t + 0) * HH + tid], c0);
      c1 = fmaf(attn[t + 1], o1b[(t + 1) * HH + tid], c1);
      c2 = fmaf(attn[t + 2], o1b[(t + 2) * HH + tid], c2);
      c3 = fmaf(attn[t + 3], o1b[(t + 3) * HH + tid], c3);
    }
    ctx[tid] = ((c0 + c1) + (c2 + c3)) * invZ;
  }
  __syncthreads();
  if (tid < HH) {
    float d0 = 0.f, d1 = 0.f;
    for (int k = 0; k < HH; k += 2) {
      d0 = fmaf(fc1T[k * HH + tid], ctx[k], d0);
      d1 = fmaf(fc1T[(k + 1) * HH + tid], ctx[k + 1], d1);
    }
    h1[tid] = fmaxf(d0 + d1 + fc1b[tid], 0.f);
  }
  __syncthreads();
  if (tid == 0) {
    float acc = fc2b[0];
    for (int k = 0; k < HH; ++k) acc = fmaf(fc2w[k], h1[k], acc);
    logits[b] = acc;
  }
}

extern "C" void kernel_launch(void* const* d_in, const int* in_sizes, int n_in,
                              void* d_out, int out_size, void* d_ws, size_t ws_size,
                              hipStream_t stream) {
  const int* texts     = (const int*)d_in[0];
  const int* lengths   = (const int*)d_in[1];
  const float* emb     = (const float*)d_in[2];
  const float* Wih0    = (const float*)d_in[3];
  const float* Whh0    = (const float*)d_in[4];
  const float* bih0    = (const float*)d_in[5];
  const float* bhh0    = (const float*)d_in[6];
  const float* Wih1    = (const float*)d_in[7];
  const float* Whh1    = (const float*)d_in[8];
  const float* bih1    = (const float*)d_in[9];
  const float* bhh1    = (const float*)d_in[10];
  const float* W1      = (const float*)d_in[11];
  const float* w2      = (const float*)d_in[12];
  const float* fc1w    = (const float*)d_in[13];
  const float* fc1b    = (const float*)d_in[14];
  const float* fc2w    = (const float*)d_in[15];
  const float* fc2b    = (const float*)d_in[16];
  float* logits = (float*)d_out;

  float* ws = (float*)d_ws;
  size_t off = 0;
  auto alloc = [&](size_t n) { float* p = ws + off; off += (n + 3) & ~(size_t)3; return p; };
  float* Wih0T  = alloc((size_t)G3 * EE);
  float* Whh0T  = alloc((size_t)G3 * HH);
  float* Wih1Tp = alloc((size_t)G3 * 152);
  float* Whh1T  = alloc((size_t)G3 * HH);
  float* W1T    = alloc((size_t)AT * HH);
  float* fc1T   = alloc((size_t)HH * HH);
  float* xwbuf  = alloc((size_t)BB * TT * G3);   // reused for xw0 then xw1
  float* out0   = alloc((size_t)BB * TT * HH);
  float* out1   = alloc((size_t)BB * TT * HH);
  float* scores = alloc((size_t)BB * TT);
  (void)ws_size; (void)in_sizes; (void)n_in; (void)out_size;

  hipLaunchKernelGGL(k_prep, dim3(256), dim3(256), 0, stream,
                     Wih0, Whh0, Wih1, Whh1, W1, fc1w,
                     Wih0T, Whh0T, Wih1Tp, Whh1T, W1T, fc1T);
  hipLaunchKernelGGL(k_xw0, dim3((BB * TT) / 32), dim3(128), 0, stream, texts, lengths, emb, Wih0T, bih0, xwbuf);
  hipLaunchKernelGGL(k_rec, dim3(BB), dim3(512), 0, stream, Whh0T, bhh0, xwbuf, lengths, out0);
  hipLaunchKernelGGL(k_xw1, dim3((BB * TT) / 32), dim3(128), 0, stream, out0, lengths, Wih1Tp, bih1, xwbuf);
  hipLaunchKernelGGL(k_rec, dim3(BB), dim3(512), 0, stream, Whh1T, bhh1, xwbuf, lengths, out1);
  hipLaunchKernelGGL(k_scores, dim3((BB * TT) / 32), dim3(256), 0, stream, out1, lengths, W1T, w2, scores);
  hipLaunchKernelGGL(k_final, dim3(BB), dim3(512), 0, stream, out1, scores, fc1T, fc1b, fc2w, fc2b, logits);
}

// Round 13
// 1069.142 us; speedup vs baseline: 1.1516x; 1.1516x over previous
//
#include <hip/hip_runtime.h>

#define TT 512
#define BB 64
#define EE 300
#define HH 150
#define G3 450
#define AT 75
#define NW 28          // v2f pairs per row-slice (56-float h window)

typedef float v2f __attribute__((ext_vector_type(2)));

__device__ __forceinline__ float fast_rcp(float x) { return __builtin_amdgcn_rcpf(x); }
__device__ __forceinline__ float sigmoid_f(float x) { return fast_rcp(1.f + __expf(-x)); }
__device__ __forceinline__ float tanh_f(float x) {
  float e = __expf(2.f * x);
  return 1.f - 2.f * fast_rcp(e + 1.f);
}

// ---------------- weight prep ----------------
// Wih0T [300][450], Whh0T/Whh1T [150][450] (k-major), Wih1Tp [152][450] padded.
__global__ void k_prep(const float* __restrict__ Wih0, const float* __restrict__ Whh0,
                       const float* __restrict__ Wih1, const float* __restrict__ Whh1,
                       const float* __restrict__ W1,   const float* __restrict__ fc1w,
                       float* __restrict__ Wih0T, float* __restrict__ Whh0T,
                       float* __restrict__ Wih1Tp, float* __restrict__ Whh1T,
                       float* __restrict__ W1T,   float* __restrict__ fc1T) {
  int tid = blockIdx.x * blockDim.x + threadIdx.x;
  int nt = gridDim.x * blockDim.x;
  for (int i = tid; i < G3 * EE; i += nt) { int r = i / EE, c = i - r * EE; Wih0T[c * G3 + r] = Wih0[i]; }
  for (int i = tid; i < G3 * HH; i += nt) { int r = i / HH, c = i - r * HH; Whh0T[c * G3 + r] = Whh0[i]; }
  for (int i = tid; i < 152 * G3; i += nt) {
    int k = i / G3, g = i - k * G3;
    Wih1Tp[i] = (k < HH) ? Wih1[g * HH + k] : 0.f;
  }
  for (int i = tid; i < G3 * HH; i += nt) { int r = i / HH, c = i - r * HH; Whh1T[c * G3 + r] = Whh1[i]; }
  for (int i = tid; i < AT * HH; i += nt) { int r = i / HH, c = i - r * HH; W1T[c * AT + r] = W1[i]; }
  for (int i = tid; i < HH * HH; i += nt) { int r = i / HH, c = i - r * HH; fc1T[c * HH + r] = fc1w[i]; }
}

// ---------------- layer-0 input projection: gather + [32768,300]@[300,450] ----------------
// Early-exit: each 32-row tile is one (b, t-range); if t0 >= len[b] the rows
// are never read by k_rec (it only reads t < len) -> skip (~48% of tiles).
__global__ __launch_bounds__(128, 2) void k_xw0(const int* __restrict__ texts,
                                                const int* __restrict__ lengths,
                                                const float* __restrict__ emb,
                                                const float* __restrict__ WihT,
                                                const float* __restrict__ bih,
                                                float* __restrict__ xw) {
  const int row0 = blockIdx.x * 32;
  if ((row0 & 511) >= lengths[row0 >> 9]) return;
  __shared__ __align__(16) float a_lds[32 * EE];
  const int tid = threadIdx.x;
  for (int p = tid; p < 32 * EE; p += 128) {
    int r = p / EE, e = p - r * EE;
    a_lds[p] = emb[(size_t)texts[row0 + r] * EE + e];
  }
  __syncthreads();
  const int g0 = tid, g1 = tid + 128, g2 = tid + 256;
  const bool has3 = (tid + 384) < G3;
  const int g3 = has3 ? tid + 384 : 0;
  float acc0[32], acc1[32], acc2[32], acc3[32];
#pragma unroll
  for (int r = 0; r < 32; ++r) { acc0[r] = 0.f; acc1[r] = 0.f; acc2[r] = 0.f; acc3[r] = 0.f; }
  const float4* a4 = reinterpret_cast<const float4*>(a_lds);
  for (int k = 0; k < EE; k += 4) {
    float wA[4], wB[4], wC[4], wD[4];
#pragma unroll
    for (int i = 0; i < 4; ++i) {
      const float* wr = WihT + (size_t)(k + i) * G3;
      wA[i] = wr[g0]; wB[i] = wr[g1]; wC[i] = wr[g2]; wD[i] = wr[g3];
    }
#pragma unroll
    for (int r = 0; r < 32; ++r) {
      const float4 av = a4[r * 75 + (k >> 2)];
      acc0[r] = fmaf(av.x, wA[0], acc0[r]); acc0[r] = fmaf(av.y, wA[1], acc0[r]);
      acc0[r] = fmaf(av.z, wA[2], acc0[r]); acc0[r] = fmaf(av.w, wA[3], acc0[r]);
      acc1[r] = fmaf(av.x, wB[0], acc1[r]); acc1[r] = fmaf(av.y, wB[1], acc1[r]);
      acc1[r] = fmaf(av.z, wB[2], acc1[r]); acc1[r] = fmaf(av.w, wB[3], acc1[r]);
      acc2[r] = fmaf(av.x, wC[0], acc2[r]); acc2[r] = fmaf(av.y, wC[1], acc2[r]);
      acc2[r] = fmaf(av.z, wC[2], acc2[r]); acc2[r] = fmaf(av.w, wC[3], acc2[r]);
      acc3[r] = fmaf(av.x, wD[0], acc3[r]); acc3[r] = fmaf(av.y, wD[1], acc3[r]);
      acc3[r] = fmaf(av.z, wD[2], acc3[r]); acc3[r] = fmaf(av.w, wD[3], acc3[r]);
    }
  }
  const float b0 = bih[g0], b1 = bih[g1], b2 = bih[g2], b3 = bih[g3];
#pragma unroll
  for (int r = 0; r < 32; ++r) {
    float* o = xw + (size_t)(row0 + r) * G3;
    o[g0] = acc0[r] + b0; o[g1] = acc1[r] + b1; o[g2] = acc2[r] + b2;
    if (has3) o[g3] = acc3[r] + b3;
  }
}

// ---------------- layer-1 input projection: [32768,150]@[150,450] ----------------
__global__ __launch_bounds__(128, 2) void k_xw1(const float* __restrict__ in,
                                                const int* __restrict__ lengths,
                                                const float* __restrict__ WihTp,
                                                const float* __restrict__ bih,
                                                float* __restrict__ xw) {
  const int row0 = blockIdx.x * 32;
  if ((row0 & 511) >= lengths[row0 >> 9]) return;
  __shared__ __align__(16) float a_lds[32 * 152];
  const int tid = threadIdx.x;
  for (int p = tid; p < 32 * 152; p += 128) {
    int r = p / 152, e = p - r * 152;
    a_lds[p] = (e < HH) ? in[(size_t)(row0 + r) * HH + e] : 0.f;
  }
  __syncthreads();
  const int g0 = tid, g1 = tid + 128, g2 = tid + 256;
  const bool has3 = (tid + 384) < G3;
  const int g3 = has3 ? tid + 384 : 0;
  float acc0[32], acc1[32], acc2[32], acc3[32];
#pragma unroll
  for (int r = 0; r < 32; ++r) { acc0[r] = 0.f; acc1[r] = 0.f; acc2[r] = 0.f; acc3[r] = 0.f; }
  const float4* a4 = reinterpret_cast<const float4*>(a_lds);
  for (int k = 0; k < 152; k += 4) {
    float wA[4], wB[4], wC[4], wD[4];
#pragma unroll
    for (int i = 0; i < 4; ++i) {
      const float* wr = WihTp + (size_t)(k + i) * G3;
      wA[i] = wr[g0]; wB[i] = wr[g1]; wC[i] = wr[g2]; wD[i] = wr[g3];
    }
#pragma unroll
    for (int r = 0; r < 32; ++r) {
      const float4 av = a4[r * 38 + (k >> 2)];
      acc0[r] = fmaf(av.x, wA[0], acc0[r]); acc0[r] = fmaf(av.y, wA[1], acc0[r]);
      acc0[r] = fmaf(av.z, wA[2], acc0[r]); acc0[r] = fmaf(av.w, wA[3], acc0[r]);
      acc1[r] = fmaf(av.x, wB[0], acc1[r]); acc1[r] = fmaf(av.y, wB[1], acc1[r]);
      acc1[r] = fmaf(av.z, wB[2], acc1[r]); acc1[r] = fmaf(av.w, wB[3], acc1[r]);
      acc2[r] = fmaf(av.x, wC[0], acc2[r]); acc2[r] = fmaf(av.y, wC[1], acc2[r]);
      acc2[r] = fmaf(av.z, wC[2], acc2[r]); acc2[r] = fmaf(av.w, wC[3], acc2[r]);
      acc3[r] = fmaf(av.x, wD[0], acc3[r]); acc3[r] = fmaf(av.y, wD[1], acc3[r]);
      acc3[r] = fmaf(av.z, wD[2], acc3[r]); acc3[r] = fmaf(av.w, wD[3], acc3[r]);
    }
  }
  const float b0 = bih[g0], b1 = bih[g1], b2 = bih[g2], b3 = bih[g3];
#pragma unroll
  for (int r = 0; r < 32; ++r) {
    float* o = xw + (size_t)(row0 + r) * G3;
    o[g0] = acc0[r] + b0; o[g1] = acc1[r] + b1; o[g2] = acc2[r] + b2;
    if (has3) o[g3] = acc3[r] + b3;
  }
}

// ---------------- GRU recurrence (round-10 proven form: 359us) ----------------
// Thread (g, j) owns gate rows {j, j+150, j+300} restricted to k-slice g.
// Rounds 6-12 falsified every local alternative (global ring, readlane pack,
// L1 split, pkfma, xw prefetch); this form is the local optimum -- frozen.
__global__ __launch_bounds__(512, 2) void k_rec(const float* __restrict__ WhhT,
                                                const float* __restrict__ bhh,
                                                const float* __restrict__ xw,
                                                const int* __restrict__ lengths,
                                                float* __restrict__ out) {
  const int b = blockIdx.x;
  const int tid = threadIdx.x;
  __shared__ __align__(16) float h_lds[152];      // 150 used; pad zeros
  __shared__ float part[2][G3 + 6];
  const int len = lengths[b];

  int g = tid / 150;                               // 0,1,2 worker slices; 3 = inactive
  const bool worker = g < 3;
  const int gg = worker ? g : 2;
  const int j = worker ? (tid - 150 * g) : 0;
  const int kreal_end = (gg == 2) ? 150 : 48 * (gg + 1);
  const int h4base = 12 * gg;                      // float4 index of window start (48g/4)

  v2f w[3][NW];
#pragma unroll
  for (int r = 0; r < 3; ++r) {
    const int row = j + 150 * r;
#pragma unroll
    for (int q = 0; q < NW; ++q) {
      const int k0 = 48 * gg + 2 * q;
      const int k1 = k0 + 1;
      w[r][q][0] = (worker && k0 < kreal_end) ? WhhT[k0 * G3 + row] : 0.f;
      w[r][q][1] = (worker && k1 < kreal_end) ? WhhT[k1 * G3 + row] : 0.f;
    }
  }
  const float bias_r = bhh[j];
  const float bias_z = bhh[j + 150];
  const float bias_n = bhh[j + 300];

  for (int p = tid; p < 152; p += 512) h_lds[p] = 0.f;
  float h_reg = 0.f;                               // h[j] for g0 threads
  __syncthreads();

  const float* xwb = xw + (size_t)b * TT * G3;
  float* outb = out + (size_t)b * TT * HH;
  const float4* h4 = reinterpret_cast<const float4*>(h_lds);

  for (int t = 0; t < len; ++t) {
    float xr = 0.f, xz = 0.f, xn = 0.f;
    if (tid < HH) {
      const float* xwt = xwb + (size_t)t * G3;
      xr = xwt[tid]; xz = xwt[tid + HH]; xn = xwt[tid + 2 * HH];
    }
    v2f ar0 = {0.f, 0.f}, ar1 = {0.f, 0.f};
    v2f az0 = {0.f, 0.f}, az1 = {0.f, 0.f};
    v2f an0 = {0.f, 0.f}, an1 = {0.f, 0.f};
#pragma unroll
    for (int q = 0; q < 14; ++q) {
      const float4 hv = h4[h4base + q];
      const v2f hx = {hv.x, hv.y};
      const v2f hy = {hv.z, hv.w};
      ar0 = __builtin_elementwise_fma(w[0][2 * q],     hx, ar0);
      ar1 = __builtin_elementwise_fma(w[0][2 * q + 1], hy, ar1);
      az0 = __builtin_elementwise_fma(w[1][2 * q],     hx, az0);
      az1 = __builtin_elementwise_fma(w[1][2 * q + 1], hy, az1);
      an0 = __builtin_elementwise_fma(w[2][2 * q],     hx, an0);
      an1 = __builtin_elementwise_fma(w[2][2 * q + 1], hy, an1);
    }
    const float pr = (ar0[0] + ar0[1]) + (ar1[0] + ar1[1]);
    const float pz = (az0[0] + az0[1]) + (az1[0] + az1[1]);
    const float pn = (an0[0] + an0[1]) + (an1[0] + an1[1]);
    if (worker && g > 0) {
      part[g - 1][j] = pr;
      part[g - 1][j + 150] = pz;
      part[g - 1][j + 300] = pn;
    }
    __syncthreads();

    if (tid < HH) {
      const float hr = pr + part[0][tid] + part[1][tid] + bias_r;
      const float hz = pz + part[0][tid + 150] + part[1][tid + 150] + bias_z;
      const float hn = pn + part[0][tid + 300] + part[1][tid + 300] + bias_n;
      const float r = sigmoid_f(xr + hr);
      const float z = sigmoid_f(xz + hz);
      const float n = tanh_f(xn + r * hn);
      const float hnew = (1.f - z) * n + z * h_reg;
      h_reg = hnew;
      h_lds[tid] = hnew;
      outb[(size_t)t * HH + tid] = hnew;
    }
    __syncthreads();
  }
  // pad_packed_sequence pads with zeros past length
  const int rem = (TT - len) * HH;
  float* outp = outb + (size_t)len * HH;
  for (int p = tid; p < rem; p += 512) outp[p] = 0.f;
}

// ---------------- attention scores: tanh(out1 @ W1^T) @ w2^T ----------------
// Rewritten (round 13): old version re-read each out1 row from GLOBAL 75x
// (once per attention column) with divergent addresses -- the suspected bulk
// of the constant ~425us non-rec time. Now: stage the 32-row tile in LDS once
// (75x less global traffic), thread a<75 computes column a for all 32 rows
// with coalesced W1T reads; partials via pp[32][77] (77 stride -> 13r+a mod 32
// distinct -> conflict-free reduce).
__global__ __launch_bounds__(128, 2) void k_scores(const float* __restrict__ out1,
                                                   const int* __restrict__ lengths,
                                                   const float* __restrict__ W1T,
                                                   const float* __restrict__ w2,
                                                   float* __restrict__ scores) {
  const int row0 = blockIdx.x * 32;
  const int tid = threadIdx.x;
  if ((row0 & 511) >= lengths[row0 >> 9]) {
    if (tid < 32) scores[row0 + tid] = 0.f;
    return;
  }
  __shared__ __align__(16) float a_lds[32 * 152];
  __shared__ float pp[32][77];
  for (int p = tid; p < 32 * 152; p += 128) {
    int r = p / 152, e = p - r * 152;
    a_lds[p] = (e < HH) ? out1[(size_t)(row0 + r) * HH + e] : 0.f;
  }
  __syncthreads();
  if (tid < AT) {
    const int a = tid;
    float acc[32];
#pragma unroll
    for (int r = 0; r < 32; ++r) acc[r] = 0.f;
    const float4* a4 = reinterpret_cast<const float4*>(a_lds);
    for (int k = 0; k < 148; k += 4) {
      const float w0 = W1T[(k + 0) * AT + a];
      const float w1 = W1T[(k + 1) * AT + a];
      const float w2v = W1T[(k + 2) * AT + a];
      const float w3 = W1T[(k + 3) * AT + a];
#pragma unroll
      for (int r = 0; r < 32; ++r) {
        const float4 av = a4[r * 38 + (k >> 2)];
        acc[r] = fmaf(av.x, w0, acc[r]);
        acc[r] = fmaf(av.y, w1, acc[r]);
        acc[r] = fmaf(av.z, w2v, acc[r]);
        acc[r] = fmaf(av.w, w3, acc[r]);
      }
    }
    {
      const float w0 = W1T[148 * AT + a];
      const float w1 = W1T[149 * AT + a];
#pragma unroll
      for (int r = 0; r < 32; ++r) {
        acc[r] = fmaf(a_lds[r * 152 + 148], w0, acc[r]);
        acc[r] = fmaf(a_lds[r * 152 + 149], w1, acc[r]);
      }
    }
    const float wa = w2[a];
#pragma unroll
    for (int r = 0; r < 32; ++r) pp[r][a] = tanh_f(acc[r]) * wa;
  }
  __syncthreads();
  if (tid < 32) {
    float s0 = 0.f, s1 = 0.f, s2 = 0.f;
    for (int a = 0; a < 75; a += 3) {
      s0 += pp[tid][a];
      s1 += pp[tid][a + 1];
      s2 += pp[tid][a + 2];
    }
    scores[row0 + tid] = (s0 + s1) + s2;
  }
}

// ---------------- softmax + context + classifier head (per batch) ----------------
__global__ __launch_bounds__(512) void k_final(const float* __restrict__ out1,
                                               const float* __restrict__ scores,
                                               const float* __restrict__ fc1T,
                                               const float* __restrict__ fc1b,
                                               const float* __restrict__ fc2w,
                                               const float* __restrict__ fc2b,
                                               float* __restrict__ logits) {
  const int b = blockIdx.x;
  const int tid = threadIdx.x;
  __shared__ float attn[TT];
  __shared__ float red[16];
  __shared__ float ctx[152];
  __shared__ float h1[152];

  float sv = scores[b * TT + tid];
  float m = sv;
#pragma unroll
  for (int off = 32; off > 0; off >>= 1) m = fmaxf(m, __shfl_xor(m, off));
  const int wave = tid >> 6;
  if ((tid & 63) == 0) red[wave] = m;
  __syncthreads();
  if (tid == 0) {
    float mm = red[0];
#pragma unroll
    for (int i = 1; i < 8; ++i) mm = fmaxf(mm, red[i]);
    red[8] = mm;
  }
  __syncthreads();
  const float e = __expf(sv - red[8]);
  attn[tid] = e;
  float zz = e;
#pragma unroll
  for (int off = 32; off > 0; off >>= 1) zz += __shfl_xor(zz, off);
  if ((tid & 63) == 0) red[wave] = zz;
  __syncthreads();
  if (tid == 0) {
    float ss = 0.f;
#pragma unroll
    for (int i = 0; i < 8; ++i) ss += red[i];
    red[9] = ss;
  }
  __syncthreads();
  const float invZ = 1.f / red[9];

  if (tid < HH) {
    const float* o1b = out1 + (size_t)b * TT * HH;
    float c0 = 0.f, c1 = 0.f, c2 = 0.f, c3 = 0.f;
    for (int t = 0; t < TT; t += 4) {
      c0 = fmaf(attn[t + 0], o1b[(t + 0) * HH + tid], c0);
      c1 = fmaf(attn[t + 1], o1b[(t + 1) * HH + tid], c1);
      c2 = fmaf(attn[t + 2], o1b[(t + 2) * HH + tid], c2);
      c3 = fmaf(attn[t + 3], o1b[(t + 3) * HH + tid], c3);
    }
    ctx[tid] = ((c0 + c1) + (c2 + c3)) * invZ;
  }
  __syncthreads();
  if (tid < HH) {
    float d0 = 0.f, d1 = 0.f;
    for (int k = 0; k < HH; k += 2) {
      d0 = fmaf(fc1T[k * HH + tid], ctx[k], d0);
      d1 = fmaf(fc1T[(k + 1) * HH + tid], ctx[k + 1], d1);
    }
    h1[tid] = fmaxf(d0 + d1 + fc1b[tid], 0.f);
  }
  __syncthreads();
  if (tid == 0) {
    float acc = fc2b[0];
    for (int k = 0; k < HH; ++k) acc = fmaf(fc2w[k], h1[k], acc);
    logits[b] = acc;
  }
}

extern "C" void kernel_launch(void* const* d_in, const int* in_sizes, int n_in,
                              void* d_out, int out_size, void* d_ws, size_t ws_size,
                              hipStream_t stream) {
  const int* texts     = (const int*)d_in[0];
  const int* lengths   = (const int*)d_in[1];
  const float* emb     = (const float*)d_in[2];
  const float* Wih0    = (const float*)d_in[3];
  const float* Whh0    = (const float*)d_in[4];
  const float* bih0    = (const float*)d_in[5];
  const float* bhh0    = (const float*)d_in[6];
  const float* Wih1    = (const float*)d_in[7];
  const float* Whh1    = (const float*)d_in[8];
  const float* bih1    = (const float*)d_in[9];
  const float* bhh1    = (const float*)d_in[10];
  const float* W1      = (const float*)d_in[11];
  const float* w2      = (const float*)d_in[12];
  const float* fc1w    = (const float*)d_in[13];
  const float* fc1b    = (const float*)d_in[14];
  const float* fc2w    = (const float*)d_in[15];
  const float* fc2b    = (const float*)d_in[16];
  float* logits = (float*)d_out;

  float* ws = (float*)d_ws;
  size_t off = 0;
  auto alloc = [&](size_t n) { float* p = ws + off; off += (n + 3) & ~(size_t)3; return p; };
  float* Wih0T  = alloc((size_t)G3 * EE);
  float* Whh0T  = alloc((size_t)G3 * HH);
  float* Wih1Tp = alloc((size_t)G3 * 152);
  float* Whh1T  = alloc((size_t)G3 * HH);
  float* W1T    = alloc((size_t)AT * HH);
  float* fc1T   = alloc((size_t)HH * HH);
  float* xwbuf  = alloc((size_t)BB * TT * G3);   // reused for xw0 then xw1
  float* out0   = alloc((size_t)BB * TT * HH);
  float* out1   = alloc((size_t)BB * TT * HH);
  float* scores = alloc((size_t)BB * TT);
  (void)ws_size; (void)in_sizes; (void)n_in; (void)out_size;

  hipLaunchKernelGGL(k_prep, dim3(256), dim3(256), 0, stream,
                     Wih0, Whh0, Wih1, Whh1, W1, fc1w,
                     Wih0T, Whh0T, Wih1Tp, Whh1T, W1T, fc1T);
  hipLaunchKernelGGL(k_xw0, dim3((BB * TT) / 32), dim3(128), 0, stream, texts, lengths, emb, Wih0T, bih0, xwbuf);
  hipLaunchKernelGGL(k_rec, dim3(BB), dim3(512), 0, stream, Whh0T, bhh0, xwbuf, lengths, out0);
  hipLaunchKernelGGL(k_xw1, dim3((BB * TT) / 32), dim3(128), 0, stream, out0, lengths, Wih1Tp, bih1, xwbuf);
  hipLaunchKernelGGL(k_rec, dim3(BB), dim3(512), 0, stream, Whh1T, bhh1, xwbuf, lengths, out1);
  hipLaunchKernelGGL(k_scores, dim3((BB * TT) / 32), dim3(128), 0, stream, out1, lengths, W1T, w2, scores);
  hipLaunchKernelGGL(k_final, dim3(BB), dim3(512), 0, stream, out1, scores, fc1T, fc1b, fc2w, fc2b, logits);
}